// Round 11
// baseline (286.223 us; speedup 1.0000x reference)
//
#include <hip/hip_runtime.h>
#include <hip/hip_fp16.h>
#include <math.h>

#define N_NODES 100000
#define N_EDGES 3200000
#define DIM 16
#define NSZ (N_NODES * DIM)

#define NPB 128         // nodes per bucket (bucket = col>>7, cl = col&127)
#define NBUCK 782       // ceil(100000/128); last bucket has 32 valid nodes
#define NBLK 512        // sort partition blocks
#define EPB 6256        // edges per partition block; multiple of 4 for int4
#define CAP 4864        // aggregate LDS tile (mean 4096, +12 sigma single-tile)
#define PRK 5           // ceil(CAP/1024) register-carried entries per thread
#define AGG_GRID 512    // persistent aggregate blocks: 2/CU exactly

// packed entry: [63:47]=col(17) [46:30]=row(17) [29:0]=w bits>>2
typedef float nvec4 __attribute__((ext_vector_type(4)));

// ---- 1) prep: f32 state -> f16 table (3.2MB, L2-resident for gathers);
//         out1=x, out2=-x; per-block 782-histogram -> tbl + totals.
//         LAST block (ticket) also scans totals -> off (folds scan_off). ----
__global__ __launch_bounds__(512)
void prep(const float* __restrict__ state, const int* __restrict__ col,
          __half* __restrict__ hs, float* __restrict__ out,
          unsigned* __restrict__ tbl, int* __restrict__ totals,
          int* __restrict__ ticket, int* __restrict__ off) {
    __shared__ int hcnt[NBUCK];                 // 3.1 KB
    __shared__ int s_last;
    __shared__ int wsum[8];
    int t = threadIdx.x, blk = blockIdx.x;
    for (int j = t; j < NBUCK; j += 512) hcnt[j] = 0;
    int gid = blk * 512 + t, gsz = NBLK * 512;
    for (int i = gid; i < NSZ / 4; i += gsz) {
        nvec4 v = __builtin_nontemporal_load(&((const nvec4*)state)[i]);
        union { __half2 h[2]; float2 f; } u;
        u.h[0] = __floats2half2_rn(v.x, v.y);
        u.h[1] = __floats2half2_rn(v.z, v.w);
        ((float2*)hs)[i] = u.f;                 // reused by aggregate: keep cached
        __builtin_nontemporal_store(v, &((nvec4*)(out + 1 * (size_t)NSZ))[i]);
        nvec4 nv = {-v.x, -v.y, -v.z, -v.w};
        __builtin_nontemporal_store(nv, &((nvec4*)(out + 2 * (size_t)NSZ))[i]);
    }
    __syncthreads();
    int e0 = blk * EPB;
    int eN = e0 + EPB; if (eN > N_EDGES) eN = N_EDGES;
    int nch = (eN - e0) >> 2;
    const int4* c4p = (const int4*)(col + e0);
    for (int i = t; i < nch; i += 512) {
        int4 c = c4p[i];
        atomicAdd(&hcnt[c.x >> 7], 1);
        atomicAdd(&hcnt[c.y >> 7], 1);
        atomicAdd(&hcnt[c.z >> 7], 1);
        atomicAdd(&hcnt[c.w >> 7], 1);
    }
    __syncthreads();
    for (int j = t; j < NBUCK; j += 512) {
        int c = hcnt[j];
        tbl[(size_t)j * NBLK + blk] = (unsigned)c;
        if (c) atomicAdd(&totals[j], c);
    }
    // ---- last-block scan of totals -> off[0..782] ----
    __threadfence();
    if (t == 0) s_last = (atomicAdd(ticket, 1) == NBLK - 1) ? 1 : 0;
    __syncthreads();
    if (s_last) {
        __threadfence();
        int i0 = 2 * t, i1 = 2 * t + 1;
        int v0 = (i0 < NBUCK) ? totals[i0] : 0;
        int v1 = (i1 < NBUCK) ? totals[i1] : 0;
        int p = v0 + v1, ps = p;
        #pragma unroll
        for (int d = 1; d < 64; d <<= 1) {
            int u = __shfl_up(ps, d, 64);
            if ((t & 63) >= d) ps += u;
        }
        if ((t & 63) == 63) wsum[t >> 6] = ps;
        __syncthreads();
        int wid = t >> 6, wbase = 0;
        #pragma unroll
        for (int k = 0; k < 8; ++k) wbase += (k < wid) ? wsum[k] : 0;
        int ex = wbase + ps - p;
        if (i0 <= NBUCK) off[i0] = ex;
        if (i1 <= NBUCK) off[i1] = ex + v0;
    }
}

// ---- 2) tbl counts -> global write bases, in place (shfl scan) ----
__global__ __launch_bounds__(512)
void base_scan(unsigned* __restrict__ tbl, const int* __restrict__ off) {
    __shared__ int wsum[8];
    int b = blockIdx.x, t = threadIdx.x;
    int v = (int)tbl[(size_t)b * NBLK + t];
    int ps = v;
    #pragma unroll
    for (int d = 1; d < 64; d <<= 1) {
        int u = __shfl_up(ps, d, 64);
        if ((t & 63) >= d) ps += u;
    }
    if ((t & 63) == 63) wsum[t >> 6] = ps;
    __syncthreads();
    int wid = t >> 6, wbase = 0;
    #pragma unroll
    for (int k = 0; k < 8; ++k) wbase += (k < wid) ? wsum[k] : 0;
    tbl[(size_t)b * NBLK + t] = (unsigned)(off[b] + wbase + ps - v);   // excl
}

// ---- 3) sort_write: per-block LDS radix to 782 buckets -> runs of ~8
//         entries (full 64B lines). diff[b] = gbase[b] - lstart[b]. ----
__global__ __launch_bounds__(512)
void sort_write(const int* __restrict__ row, const int* __restrict__ col,
                const float* __restrict__ w, const unsigned* __restrict__ tbl,
                const int* __restrict__ off,
                unsigned long long* __restrict__ packed) {
    __shared__ unsigned long long sbuf[EPB];   // 50,048 B
    __shared__ int cur[NBUCK];                 // counts -> scatter cursor
    __shared__ int diff[NBUCK];                // gbase -> gbase - lstart
    __shared__ int wsum[8];                    // total ~56.4 KB
    int t = threadIdx.x, blk = blockIdx.x;
    int e0 = blk * EPB;
    int eN = e0 + EPB; if (eN > N_EDGES) eN = N_EDGES;
    int cnt = eN - e0;

    for (int j = t; j < NBUCK; j += 512) {     // bases + derived counts
        int b0 = (int)tbl[(size_t)j * NBLK + blk];
        int b1 = (blk == NBLK - 1) ? off[j + 1]
                                   : (int)tbl[(size_t)j * NBLK + blk + 1];
        diff[j] = b0;                          // gbase (temp)
        cur[j] = b1 - b0;                      // count
    }
    __syncthreads();
    {   // pairwise shfl exclusive scan over 1024 positions (782 live)
        int i0 = 2 * t, i1 = 2 * t + 1;
        int v0 = (i0 < NBUCK) ? cur[i0] : 0;
        int v1 = (i1 < NBUCK) ? cur[i1] : 0;
        int p = v0 + v1, ps = p;
        #pragma unroll
        for (int d = 1; d < 64; d <<= 1) {
            int u = __shfl_up(ps, d, 64);
            if ((t & 63) >= d) ps += u;
        }
        if ((t & 63) == 63) wsum[t >> 6] = ps;
        __syncthreads();
        int wid = t >> 6, wbase = 0;
        #pragma unroll
        for (int k = 0; k < 8; ++k) wbase += (k < wid) ? wsum[k] : 0;
        int ex = wbase + ps - p;
        if (i0 < NBUCK) { diff[i0] -= ex;      cur[i0] = ex; }
        if (i1 < NBUCK) { diff[i1] -= ex + v0; cur[i1] = ex + v0; }
    }
    __syncthreads();
    {   // single edge pass: int4 loads, LDS scatter by bucket
        int nch = cnt >> 2;
        const int4*   c4p = (const int4*)(col + e0);
        const int4*   r4p = (const int4*)(row + e0);
        const float4* w4p = (const float4*)(w + e0);
        for (int i = t; i < nch; i += 512) {
            int4 c = c4p[i]; int4 r = r4p[i]; float4 ww = w4p[i];
            int pos;
            pos = atomicAdd(&cur[c.x >> 7], 1);
            sbuf[pos] = ((unsigned long long)(unsigned)c.x << 47)
                      | ((unsigned long long)(unsigned)r.x << 30)
                      | (unsigned long long)(__float_as_uint(ww.x) >> 2);
            pos = atomicAdd(&cur[c.y >> 7], 1);
            sbuf[pos] = ((unsigned long long)(unsigned)c.y << 47)
                      | ((unsigned long long)(unsigned)r.y << 30)
                      | (unsigned long long)(__float_as_uint(ww.y) >> 2);
            pos = atomicAdd(&cur[c.z >> 7], 1);
            sbuf[pos] = ((unsigned long long)(unsigned)c.z << 47)
                      | ((unsigned long long)(unsigned)r.z << 30)
                      | (unsigned long long)(__float_as_uint(ww.z) >> 2);
            pos = atomicAdd(&cur[c.w >> 7], 1);
            sbuf[pos] = ((unsigned long long)(unsigned)c.w << 47)
                      | ((unsigned long long)(unsigned)r.w << 30)
                      | (unsigned long long)(__float_as_uint(ww.w) >> 2);
        }
    }
    __syncthreads();
    for (int i = t; i < cnt; i += 512) {       // dense sweep; bucket from entry
        unsigned long long pv = sbuf[i];
        int b = (int)(pv >> 54);               // col>>7
        __builtin_nontemporal_store(pv, &packed[diff[b] + i]);
    }
}

// ---- 4) aggregate: PERSISTENT 512 blocks x 1024 thr (2/CU, 32 waves/CU).
//         Work queue removes the 270-block half-occupancy tail.
//         128 nodes x 4 dim-lanes x 2 edge-subgroups per bucket. ----
__global__ __launch_bounds__(1024, 8)
void aggregate(const float* __restrict__ state, const __half2* __restrict__ hs2,
               const int* __restrict__ off,
               const unsigned long long* __restrict__ packed,
               int* __restrict__ qctr, float* __restrict__ out) {
    __shared__ unsigned long long sbuf[CAP];       // 38,912 B
    __shared__ int s_cnt[NPB], s_start[NPB], s_cur[NPB];
    __shared__ int s_wsum, s_nb;
    int t = threadIdx.x;
    int q = t & 3, sub = (t >> 2) & 1, g = t >> 3;   // node group 0..127
    const uint2* hsu = (const uint2*)hs2;            // 8 B = 4 halfs per lane

    int nb = blockIdx.x;
    while (nb < NBUCK) {
        int beg = off[nb], end = off[nb + 1];
        int n = nb * NPB + g;
        bool valid = (n < N_NODES);
        float4 xx = valid ? ((const float4*)state)[n * 4 + q]
                          : make_float4(0.f, 0.f, 0.f, 0.f);
        float4 acc = {0.f, 0.f, 0.f, 0.f};

        for (int tbeg = beg; tbeg < end; tbeg += CAP) {
            int tend = tbeg + CAP; if (tend > end) tend = end;
            if (t < NPB) s_cnt[t] = 0;
            __syncthreads();

            // phase 1: coalesced read into registers; LDS cl-histogram
            unsigned long long pr[PRK];
            #pragma unroll
            for (int k = 0; k < PRK; ++k) {
                int e = tbeg + t + k * 1024;
                if (e < tend) {
                    pr[k] = __builtin_nontemporal_load(&packed[e]);
                    atomicAdd(&s_cnt[(unsigned)(pr[k] >> 47) & 127u], 1);
                }
            }
            __syncthreads();

            // phase 2: 128-entry exclusive scan on waves 0,1
            {
                int v = 0, ps = 0;
                if (t < NPB) {
                    v = s_cnt[t]; ps = v;
                    #pragma unroll
                    for (int d = 1; d < 64; d <<= 1) {
                        int u = __shfl_up(ps, d, 64);
                        if ((t & 63) >= d) ps += u;
                    }
                }
                if (t == 63) s_wsum = ps;
                __syncthreads();
                if (t < NPB) {
                    int ex = ps - v + ((t >= 64) ? s_wsum : 0);
                    s_start[t] = ex;
                    s_cur[t] = ex;
                }
            }
            __syncthreads();

            // phase 3: scatter from registers
            #pragma unroll
            for (int k = 0; k < PRK; ++k) {
                int e = tbeg + t + k * 1024;
                if (e < tend) {
                    int cl = (int)((pr[k] >> 47) & 127u);
                    int pos = atomicAdd(&s_cur[cl], 1);
                    sbuf[pos] = pr[k];
                }
            }
            __syncthreads();

            // phase 4: owner-computes; subgroup takes every 2nd edge, unroll-4
            {
                int es = s_start[g], ee = s_cur[g];
                int e = es + sub;
                for (; e + 6 < ee; e += 8) {
                    unsigned long long p0 = sbuf[e];
                    unsigned long long p1 = sbuf[e + 2];
                    unsigned long long p2 = sbuf[e + 4];
                    unsigned long long p3 = sbuf[e + 6];
                    uint2 h0 = hsu[(unsigned)((p0 >> 30) & 0x1FFFFu) * 4u + q];
                    uint2 h1 = hsu[(unsigned)((p1 >> 30) & 0x1FFFFu) * 4u + q];
                    uint2 h2 = hsu[(unsigned)((p2 >> 30) & 0x1FFFFu) * 4u + q];
                    uint2 h3 = hsu[(unsigned)((p3 >> 30) & 0x1FFFFu) * 4u + q];
                    #pragma unroll
                    for (int j = 0; j < 4; ++j) {
                        unsigned long long p = (j == 0) ? p0 : (j == 1) ? p1
                                             : (j == 2) ? p2 : p3;
                        uint2 hb = (j == 0) ? h0 : (j == 1) ? h1
                                 : (j == 2) ? h2 : h3;
                        float we = __uint_as_float(((unsigned)p & 0x3FFFFFFFu) << 2);
                        float2 lo = __half22float2(*(const __half2*)&hb.x);
                        float2 hi = __half22float2(*(const __half2*)&hb.y);
                        acc.x += __sinf(lo.x - xx.x) * we;
                        acc.y += __sinf(lo.y - xx.y) * we;
                        acc.z += __sinf(hi.x - xx.z) * we;
                        acc.w += __sinf(hi.y - xx.w) * we;
                    }
                }
                for (; e < ee; e += 2) {
                    unsigned long long p = sbuf[e];
                    uint2 hb = hsu[(unsigned)((p >> 30) & 0x1FFFFu) * 4u + q];
                    float we = __uint_as_float(((unsigned)p & 0x3FFFFFFFu) << 2);
                    float2 lo = __half22float2(*(const __half2*)&hb.x);
                    float2 hi = __half22float2(*(const __half2*)&hb.y);
                    acc.x += __sinf(lo.x - xx.x) * we;
                    acc.y += __sinf(lo.y - xx.y) * we;
                    acc.z += __sinf(hi.x - xx.z) * we;
                    acc.w += __sinf(hi.y - xx.w) * we;
                }
            }
            __syncthreads();
        }

        // merge 2 subgroups (lanes t, t^4 — same wave, same g and q)
        acc.x += __shfl_xor(acc.x, 4, 64); acc.y += __shfl_xor(acc.y, 4, 64);
        acc.z += __shfl_xor(acc.z, 4, 64); acc.w += __shfl_xor(acc.w, 4, 64);

        if (valid && sub == 0) {
            // sub0 lanes write consecutive 16B chunks: full 64B lines per wave
            float4 th = make_float4(tanhf(acc.x), tanhf(acc.y),
                                    tanhf(acc.z), tanhf(acc.w));
            int gdx = n * 4 + q;
            nvec4 v0 = {th.x - xx.x, th.y - xx.y, th.z - xx.z, th.w - xx.w};
            nvec4 v3 = {acc.x, acc.y, acc.z, acc.w};
            nvec4 v4 = {th.x, th.y, th.z, th.w};
            __builtin_nontemporal_store(v0, &((nvec4*)(out + 0 * (size_t)NSZ))[gdx]);
            __builtin_nontemporal_store(v3, &((nvec4*)(out + 3 * (size_t)NSZ))[gdx]);
            __builtin_nontemporal_store(v4, &((nvec4*)(out + 4 * (size_t)NSZ))[gdx]);
        }
        __syncthreads();
        if (t == 0) s_nb = AGG_GRID + atomicAdd(qctr, 1);
        __syncthreads();
        nb = s_nb;
    }
}

// ---- fallback (tiny ws): atomic path ----
__global__ __launch_bounds__(256)
void edge_kernel(const float* __restrict__ state, const int* __restrict__ row,
                 const int* __restrict__ col, const float* __restrict__ w,
                 float* __restrict__ agg) {
    int idx = blockIdx.x * blockDim.x + threadIdx.x;
    if (idx >= N_EDGES * 4) return;
    int e = idx >> 2, qq = idx & 3;
    int r = row[e], c = col[e];
    float we = w[e];
    const float4 xr = ((const float4*)state)[r * 4 + qq];
    const float4 xcv = ((const float4*)state)[c * 4 + qq];
    float* dst = agg + c * DIM + qq * 4;
    atomicAdd(dst + 0, sinf(xr.x - xcv.x) * we);
    atomicAdd(dst + 1, sinf(xr.y - xcv.y) * we);
    atomicAdd(dst + 2, sinf(xr.z - xcv.z) * we);
    atomicAdd(dst + 3, sinf(xr.w - xcv.w) * we);
}

__global__ __launch_bounds__(256)
void node_kernel(const float* __restrict__ state, const float* __restrict__ agg,
                 float* __restrict__ out) {
    int idx = blockIdx.x * blockDim.x + threadIdx.x;
    if (idx >= N_NODES * 4) return;
    float4 x = ((const float4*)state)[idx];
    float4 a = ((const float4*)agg)[idx];
    float4 tv = make_float4(tanhf(a.x), tanhf(a.y), tanhf(a.z), tanhf(a.w));
    ((float4*)(out + 0 * NSZ))[idx] = make_float4(tv.x - x.x, tv.y - x.y,
                                                  tv.z - x.z, tv.w - x.w);
    ((float4*)(out + 1 * NSZ))[idx] = x;
    ((float4*)(out + 2 * NSZ))[idx] = make_float4(-x.x, -x.y, -x.z, -x.w);
    ((float4*)(out + 4 * NSZ))[idx] = tv;
}

extern "C" void kernel_launch(void* const* d_in, const int* in_sizes, int n_in,
                              void* d_out, int out_size, void* d_ws, size_t ws_size,
                              hipStream_t stream) {
    const float* state = (const float*)d_in[0];
    const int*   row   = (const int*)d_in[1];
    const int*   col   = (const int*)d_in[2];
    const float* w     = (const float*)d_in[3];
    float* out = (float*)d_out;

    // ws: packed | hs (f16 state) | tbl | totals+ticket+qctr | off
    size_t packed_off = 0;
    size_t hs_off     = packed_off + (size_t)N_EDGES * 8;          // 25.6MB
    size_t tbl_off    = hs_off + (size_t)NSZ * 2;                  // +3.2MB
    size_t tot_off    = tbl_off + (size_t)NBUCK * NBLK * 4;        // +1.6MB
    size_t off_off    = tot_off + ((size_t)(NBUCK + 2) * 4 + 15) / 16 * 16;
    size_t needed     = off_off + (size_t)(NBUCK + 2) * 4;

    if (ws_size >= needed) {
        unsigned long long* packed =
            (unsigned long long*)((char*)d_ws + packed_off);
        __half* hs    = (__half*)((char*)d_ws + hs_off);
        unsigned* tbl = (unsigned*)((char*)d_ws + tbl_off);
        int* totals   = (int*)((char*)d_ws + tot_off);
        int* ticket   = totals + NBUCK;
        int* qctr     = totals + NBUCK + 1;
        int* off      = (int*)((char*)d_ws + off_off);

        (void)hipMemsetAsync(totals, 0, (size_t)(NBUCK + 2) * sizeof(int),
                             stream);
        prep<<<NBLK, 512, 0, stream>>>(state, col, hs, out, tbl, totals,
                                       ticket, off);
        base_scan<<<NBUCK, 512, 0, stream>>>(tbl, off);
        sort_write<<<NBLK, 512, 0, stream>>>(row, col, w, tbl, off, packed);
        aggregate<<<AGG_GRID, 1024, 0, stream>>>(
            state, (const __half2*)hs, off, packed, qctr, out);
    } else {
        float* agg = out + 3 * NSZ;
        (void)hipMemsetAsync(agg, 0, NSZ * sizeof(float), stream);
        edge_kernel<<<(N_EDGES * 4 + 255) / 256, 256, 0, stream>>>(
            state, row, col, w, agg);
        node_kernel<<<(N_NODES * 4 + 255) / 256, 256, 0, stream>>>(
            state, agg, out);
    }
}

// Round 12
// 182.438 us; speedup vs baseline: 1.5689x; 1.5689x over previous
//
#include <hip/hip_runtime.h>
#include <hip/hip_fp16.h>
#include <math.h>

#define N_NODES 100000
#define N_EDGES 3200000
#define DIM 16
#define NSZ (N_NODES * DIM)

#define NPB 128         // nodes per bucket (bucket = col>>7, cl = col&127)
#define NBUCK 782       // ceil(100000/128); last bucket has 32 valid nodes
#define NBLK 512        // sort partition blocks
#define EPB 6256        // edges per partition block; multiple of 4 for int4
#define CAP 4864        // aggregate LDS tile (mean 4096, +12 sigma single-tile)
#define PRK 5           // ceil(CAP/1024) register-carried entries per thread
#define AGG_GRID 512    // persistent aggregate blocks: 2/CU exactly

// packed entry: [63:47]=col(17) [46:30]=row(17) [29:0]=w bits>>2
typedef float nvec4 __attribute__((ext_vector_type(4)));

// ---- 1) prep: f32 state -> f16 table (3.2MB, L2-resident for gathers);
//         out1=x, out2=-x; per-block 782-histogram -> tbl + totals.
//         NO grid-wide fence here (R11 lesson: threadfence after bulk
//         nontemporal stores stalls the whole grid ~100us). ----
__global__ __launch_bounds__(512)
void prep(const float* __restrict__ state, const int* __restrict__ col,
          __half* __restrict__ hs, float* __restrict__ out,
          unsigned* __restrict__ tbl, int* __restrict__ totals) {
    __shared__ int hcnt[NBUCK];                 // 3.1 KB
    int t = threadIdx.x, blk = blockIdx.x;
    for (int j = t; j < NBUCK; j += 512) hcnt[j] = 0;
    int gid = blk * 512 + t, gsz = NBLK * 512;
    for (int i = gid; i < NSZ / 4; i += gsz) {
        nvec4 v = __builtin_nontemporal_load(&((const nvec4*)state)[i]);
        union { __half2 h[2]; float2 f; } u;
        u.h[0] = __floats2half2_rn(v.x, v.y);
        u.h[1] = __floats2half2_rn(v.z, v.w);
        ((float2*)hs)[i] = u.f;                 // reused by aggregate: keep cached
        __builtin_nontemporal_store(v, &((nvec4*)(out + 1 * (size_t)NSZ))[i]);
        nvec4 nv = {-v.x, -v.y, -v.z, -v.w};
        __builtin_nontemporal_store(nv, &((nvec4*)(out + 2 * (size_t)NSZ))[i]);
    }
    __syncthreads();
    int e0 = blk * EPB;
    int eN = e0 + EPB; if (eN > N_EDGES) eN = N_EDGES;
    int nch = (eN - e0) >> 2;
    const int4* c4p = (const int4*)(col + e0);
    for (int i = t; i < nch; i += 512) {
        int4 c = c4p[i];
        atomicAdd(&hcnt[c.x >> 7], 1);
        atomicAdd(&hcnt[c.y >> 7], 1);
        atomicAdd(&hcnt[c.z >> 7], 1);
        atomicAdd(&hcnt[c.w >> 7], 1);
    }
    __syncthreads();
    for (int j = t; j < NBUCK; j += 512) {
        int c = hcnt[j];
        tbl[(size_t)j * NBLK + blk] = (unsigned)c;
        if (c) atomicAdd(&totals[j], c);
    }
}

// ---- 2) exclusive scan of 782 totals -> off[0..782] ----
__global__ __launch_bounds__(512)
void scan_off(const int* __restrict__ totals, int* __restrict__ off) {
    __shared__ int wsum[8];
    int t = threadIdx.x;
    int i0 = 2 * t, i1 = 2 * t + 1;
    int v0 = (i0 < NBUCK) ? totals[i0] : 0;
    int v1 = (i1 < NBUCK) ? totals[i1] : 0;
    int p = v0 + v1, ps = p;
    #pragma unroll
    for (int d = 1; d < 64; d <<= 1) {
        int u = __shfl_up(ps, d, 64);
        if ((t & 63) >= d) ps += u;
    }
    if ((t & 63) == 63) wsum[t >> 6] = ps;
    __syncthreads();
    int wid = t >> 6, wbase = 0;
    #pragma unroll
    for (int k = 0; k < 8; ++k) wbase += (k < wid) ? wsum[k] : 0;
    int ex = wbase + ps - p;
    if (i0 <= NBUCK) off[i0] = ex;
    if (i1 <= NBUCK) off[i1] = ex + v0;
}

// ---- 3) tbl counts -> global write bases, in place (shfl scan) ----
__global__ __launch_bounds__(512)
void base_scan(unsigned* __restrict__ tbl, const int* __restrict__ off) {
    __shared__ int wsum[8];
    int b = blockIdx.x, t = threadIdx.x;
    int v = (int)tbl[(size_t)b * NBLK + t];
    int ps = v;
    #pragma unroll
    for (int d = 1; d < 64; d <<= 1) {
        int u = __shfl_up(ps, d, 64);
        if ((t & 63) >= d) ps += u;
    }
    if ((t & 63) == 63) wsum[t >> 6] = ps;
    __syncthreads();
    int wid = t >> 6, wbase = 0;
    #pragma unroll
    for (int k = 0; k < 8; ++k) wbase += (k < wid) ? wsum[k] : 0;
    tbl[(size_t)b * NBLK + t] = (unsigned)(off[b] + wbase + ps - v);   // excl
}

// ---- 4) sort_write: per-block LDS radix to 782 buckets -> runs of ~8
//         entries (full 64B lines). diff[b] = gbase[b] - lstart[b]. ----
__global__ __launch_bounds__(512)
void sort_write(const int* __restrict__ row, const int* __restrict__ col,
                const float* __restrict__ w, const unsigned* __restrict__ tbl,
                const int* __restrict__ off,
                unsigned long long* __restrict__ packed) {
    __shared__ unsigned long long sbuf[EPB];   // 50,048 B
    __shared__ int cur[NBUCK];                 // counts -> scatter cursor
    __shared__ int diff[NBUCK];                // gbase -> gbase - lstart
    __shared__ int wsum[8];                    // total ~56.4 KB
    int t = threadIdx.x, blk = blockIdx.x;
    int e0 = blk * EPB;
    int eN = e0 + EPB; if (eN > N_EDGES) eN = N_EDGES;
    int cnt = eN - e0;

    for (int j = t; j < NBUCK; j += 512) {     // bases + derived counts
        int b0 = (int)tbl[(size_t)j * NBLK + blk];
        int b1 = (blk == NBLK - 1) ? off[j + 1]
                                   : (int)tbl[(size_t)j * NBLK + blk + 1];
        diff[j] = b0;                          // gbase (temp)
        cur[j] = b1 - b0;                      // count
    }
    __syncthreads();
    {   // pairwise shfl exclusive scan over 1024 positions (782 live)
        int i0 = 2 * t, i1 = 2 * t + 1;
        int v0 = (i0 < NBUCK) ? cur[i0] : 0;
        int v1 = (i1 < NBUCK) ? cur[i1] : 0;
        int p = v0 + v1, ps = p;
        #pragma unroll
        for (int d = 1; d < 64; d <<= 1) {
            int u = __shfl_up(ps, d, 64);
            if ((t & 63) >= d) ps += u;
        }
        if ((t & 63) == 63) wsum[t >> 6] = ps;
        __syncthreads();
        int wid = t >> 6, wbase = 0;
        #pragma unroll
        for (int k = 0; k < 8; ++k) wbase += (k < wid) ? wsum[k] : 0;
        int ex = wbase + ps - p;
        if (i0 < NBUCK) { diff[i0] -= ex;      cur[i0] = ex; }
        if (i1 < NBUCK) { diff[i1] -= ex + v0; cur[i1] = ex + v0; }
    }
    __syncthreads();
    {   // single edge pass: int4 loads, LDS scatter by bucket
        int nch = cnt >> 2;
        const int4*   c4p = (const int4*)(col + e0);
        const int4*   r4p = (const int4*)(row + e0);
        const float4* w4p = (const float4*)(w + e0);
        for (int i = t; i < nch; i += 512) {
            int4 c = c4p[i]; int4 r = r4p[i]; float4 ww = w4p[i];
            int pos;
            pos = atomicAdd(&cur[c.x >> 7], 1);
            sbuf[pos] = ((unsigned long long)(unsigned)c.x << 47)
                      | ((unsigned long long)(unsigned)r.x << 30)
                      | (unsigned long long)(__float_as_uint(ww.x) >> 2);
            pos = atomicAdd(&cur[c.y >> 7], 1);
            sbuf[pos] = ((unsigned long long)(unsigned)c.y << 47)
                      | ((unsigned long long)(unsigned)r.y << 30)
                      | (unsigned long long)(__float_as_uint(ww.y) >> 2);
            pos = atomicAdd(&cur[c.z >> 7], 1);
            sbuf[pos] = ((unsigned long long)(unsigned)c.z << 47)
                      | ((unsigned long long)(unsigned)r.z << 30)
                      | (unsigned long long)(__float_as_uint(ww.z) >> 2);
            pos = atomicAdd(&cur[c.w >> 7], 1);
            sbuf[pos] = ((unsigned long long)(unsigned)c.w << 47)
                      | ((unsigned long long)(unsigned)r.w << 30)
                      | (unsigned long long)(__float_as_uint(ww.w) >> 2);
        }
    }
    __syncthreads();
    for (int i = t; i < cnt; i += 512) {       // dense sweep; bucket from entry
        unsigned long long pv = sbuf[i];
        int b = (int)(pv >> 54);               // col>>7
        __builtin_nontemporal_store(pv, &packed[diff[b] + i]);
    }
}

// ---- 5) aggregate: PERSISTENT 512 blocks x 1024 thr (2/CU, 32 waves/CU).
//         Work queue removes the 270-block half-occupancy tail.
//         128 nodes x 4 dim-lanes x 2 edge-subgroups per bucket. ----
__global__ __launch_bounds__(1024, 8)
void aggregate(const float* __restrict__ state, const __half2* __restrict__ hs2,
               const int* __restrict__ off,
               const unsigned long long* __restrict__ packed,
               int* __restrict__ qctr, float* __restrict__ out) {
    __shared__ unsigned long long sbuf[CAP];       // 38,912 B
    __shared__ int s_cnt[NPB], s_start[NPB], s_cur[NPB];
    __shared__ int s_wsum, s_nb;
    int t = threadIdx.x;
    int q = t & 3, sub = (t >> 2) & 1, g = t >> 3;   // node group 0..127
    const uint2* hsu = (const uint2*)hs2;            // 8 B = 4 halfs per lane

    int nb = blockIdx.x;
    while (nb < NBUCK) {
        int beg = off[nb], end = off[nb + 1];
        int n = nb * NPB + g;
        bool valid = (n < N_NODES);
        float4 xx = valid ? ((const float4*)state)[n * 4 + q]
                          : make_float4(0.f, 0.f, 0.f, 0.f);
        float4 acc = {0.f, 0.f, 0.f, 0.f};

        for (int tbeg = beg; tbeg < end; tbeg += CAP) {
            int tend = tbeg + CAP; if (tend > end) tend = end;
            if (t < NPB) s_cnt[t] = 0;
            __syncthreads();

            // phase 1: coalesced read into registers; LDS cl-histogram
            unsigned long long pr[PRK];
            #pragma unroll
            for (int k = 0; k < PRK; ++k) {
                int e = tbeg + t + k * 1024;
                if (e < tend) {
                    pr[k] = __builtin_nontemporal_load(&packed[e]);
                    atomicAdd(&s_cnt[(unsigned)(pr[k] >> 47) & 127u], 1);
                }
            }
            __syncthreads();

            // phase 2: 128-entry exclusive scan on waves 0,1
            {
                int v = 0, ps = 0;
                if (t < NPB) {
                    v = s_cnt[t]; ps = v;
                    #pragma unroll
                    for (int d = 1; d < 64; d <<= 1) {
                        int u = __shfl_up(ps, d, 64);
                        if ((t & 63) >= d) ps += u;
                    }
                }
                if (t == 63) s_wsum = ps;
                __syncthreads();
                if (t < NPB) {
                    int ex = ps - v + ((t >= 64) ? s_wsum : 0);
                    s_start[t] = ex;
                    s_cur[t] = ex;
                }
            }
            __syncthreads();

            // phase 3: scatter from registers
            #pragma unroll
            for (int k = 0; k < PRK; ++k) {
                int e = tbeg + t + k * 1024;
                if (e < tend) {
                    int cl = (int)((pr[k] >> 47) & 127u);
                    int pos = atomicAdd(&s_cur[cl], 1);
                    sbuf[pos] = pr[k];
                }
            }
            __syncthreads();

            // phase 4: owner-computes; subgroup takes every 2nd edge, unroll-4
            {
                int es = s_start[g], ee = s_cur[g];
                int e = es + sub;
                for (; e + 6 < ee; e += 8) {
                    unsigned long long p0 = sbuf[e];
                    unsigned long long p1 = sbuf[e + 2];
                    unsigned long long p2 = sbuf[e + 4];
                    unsigned long long p3 = sbuf[e + 6];
                    uint2 h0 = hsu[(unsigned)((p0 >> 30) & 0x1FFFFu) * 4u + q];
                    uint2 h1 = hsu[(unsigned)((p1 >> 30) & 0x1FFFFu) * 4u + q];
                    uint2 h2 = hsu[(unsigned)((p2 >> 30) & 0x1FFFFu) * 4u + q];
                    uint2 h3 = hsu[(unsigned)((p3 >> 30) & 0x1FFFFu) * 4u + q];
                    #pragma unroll
                    for (int j = 0; j < 4; ++j) {
                        unsigned long long p = (j == 0) ? p0 : (j == 1) ? p1
                                             : (j == 2) ? p2 : p3;
                        uint2 hb = (j == 0) ? h0 : (j == 1) ? h1
                                 : (j == 2) ? h2 : h3;
                        float we = __uint_as_float(((unsigned)p & 0x3FFFFFFFu) << 2);
                        float2 lo = __half22float2(*(const __half2*)&hb.x);
                        float2 hi = __half22float2(*(const __half2*)&hb.y);
                        acc.x += __sinf(lo.x - xx.x) * we;
                        acc.y += __sinf(lo.y - xx.y) * we;
                        acc.z += __sinf(hi.x - xx.z) * we;
                        acc.w += __sinf(hi.y - xx.w) * we;
                    }
                }
                for (; e < ee; e += 2) {
                    unsigned long long p = sbuf[e];
                    uint2 hb = hsu[(unsigned)((p >> 30) & 0x1FFFFu) * 4u + q];
                    float we = __uint_as_float(((unsigned)p & 0x3FFFFFFFu) << 2);
                    float2 lo = __half22float2(*(const __half2*)&hb.x);
                    float2 hi = __half22float2(*(const __half2*)&hb.y);
                    acc.x += __sinf(lo.x - xx.x) * we;
                    acc.y += __sinf(lo.y - xx.y) * we;
                    acc.z += __sinf(hi.x - xx.z) * we;
                    acc.w += __sinf(hi.y - xx.w) * we;
                }
            }
            __syncthreads();
        }

        // merge 2 subgroups (lanes t, t^4 — same wave, same g and q)
        acc.x += __shfl_xor(acc.x, 4, 64); acc.y += __shfl_xor(acc.y, 4, 64);
        acc.z += __shfl_xor(acc.z, 4, 64); acc.w += __shfl_xor(acc.w, 4, 64);

        if (valid && sub == 0) {
            // sub0 lanes write consecutive 16B chunks: full 64B lines per wave
            float4 th = make_float4(tanhf(acc.x), tanhf(acc.y),
                                    tanhf(acc.z), tanhf(acc.w));
            int gdx = n * 4 + q;
            nvec4 v0 = {th.x - xx.x, th.y - xx.y, th.z - xx.z, th.w - xx.w};
            nvec4 v3 = {acc.x, acc.y, acc.z, acc.w};
            nvec4 v4 = {th.x, th.y, th.z, th.w};
            __builtin_nontemporal_store(v0, &((nvec4*)(out + 0 * (size_t)NSZ))[gdx]);
            __builtin_nontemporal_store(v3, &((nvec4*)(out + 3 * (size_t)NSZ))[gdx]);
            __builtin_nontemporal_store(v4, &((nvec4*)(out + 4 * (size_t)NSZ))[gdx]);
        }
        __syncthreads();
        if (t == 0) s_nb = AGG_GRID + atomicAdd(qctr, 1);
        __syncthreads();
        nb = s_nb;
    }
}

// ---- fallback (tiny ws): atomic path ----
__global__ __launch_bounds__(256)
void edge_kernel(const float* __restrict__ state, const int* __restrict__ row,
                 const int* __restrict__ col, const float* __restrict__ w,
                 float* __restrict__ agg) {
    int idx = blockIdx.x * blockDim.x + threadIdx.x;
    if (idx >= N_EDGES * 4) return;
    int e = idx >> 2, qq = idx & 3;
    int r = row[e], c = col[e];
    float we = w[e];
    const float4 xr = ((const float4*)state)[r * 4 + qq];
    const float4 xcv = ((const float4*)state)[c * 4 + qq];
    float* dst = agg + c * DIM + qq * 4;
    atomicAdd(dst + 0, sinf(xr.x - xcv.x) * we);
    atomicAdd(dst + 1, sinf(xr.y - xcv.y) * we);
    atomicAdd(dst + 2, sinf(xr.z - xcv.z) * we);
    atomicAdd(dst + 3, sinf(xr.w - xcv.w) * we);
}

__global__ __launch_bounds__(256)
void node_kernel(const float* __restrict__ state, const float* __restrict__ agg,
                 float* __restrict__ out) {
    int idx = blockIdx.x * blockDim.x + threadIdx.x;
    if (idx >= N_NODES * 4) return;
    float4 x = ((const float4*)state)[idx];
    float4 a = ((const float4*)agg)[idx];
    float4 tv = make_float4(tanhf(a.x), tanhf(a.y), tanhf(a.z), tanhf(a.w));
    ((float4*)(out + 0 * NSZ))[idx] = make_float4(tv.x - x.x, tv.y - x.y,
                                                  tv.z - x.z, tv.w - x.w);
    ((float4*)(out + 1 * NSZ))[idx] = x;
    ((float4*)(out + 2 * NSZ))[idx] = make_float4(-x.x, -x.y, -x.z, -x.w);
    ((float4*)(out + 4 * NSZ))[idx] = tv;
}

extern "C" void kernel_launch(void* const* d_in, const int* in_sizes, int n_in,
                              void* d_out, int out_size, void* d_ws, size_t ws_size,
                              hipStream_t stream) {
    const float* state = (const float*)d_in[0];
    const int*   row   = (const int*)d_in[1];
    const int*   col   = (const int*)d_in[2];
    const float* w     = (const float*)d_in[3];
    float* out = (float*)d_out;

    // ws: packed | hs (f16 state) | tbl | totals+qctr | off
    size_t packed_off = 0;
    size_t hs_off     = packed_off + (size_t)N_EDGES * 8;          // 25.6MB
    size_t tbl_off    = hs_off + (size_t)NSZ * 2;                  // +3.2MB
    size_t tot_off    = tbl_off + (size_t)NBUCK * NBLK * 4;        // +1.6MB
    size_t off_off    = tot_off + ((size_t)(NBUCK + 1) * 4 + 15) / 16 * 16;
    size_t needed     = off_off + (size_t)(NBUCK + 2) * 4;

    if (ws_size >= needed) {
        unsigned long long* packed =
            (unsigned long long*)((char*)d_ws + packed_off);
        __half* hs    = (__half*)((char*)d_ws + hs_off);
        unsigned* tbl = (unsigned*)((char*)d_ws + tbl_off);
        int* totals   = (int*)((char*)d_ws + tot_off);
        int* qctr     = totals + NBUCK;
        int* off      = (int*)((char*)d_ws + off_off);

        (void)hipMemsetAsync(totals, 0, (size_t)(NBUCK + 1) * sizeof(int),
                             stream);
        prep<<<NBLK, 512, 0, stream>>>(state, col, hs, out, tbl, totals);
        scan_off<<<1, 512, 0, stream>>>(totals, off);
        base_scan<<<NBUCK, 512, 0, stream>>>(tbl, off);
        sort_write<<<NBLK, 512, 0, stream>>>(row, col, w, tbl, off, packed);
        aggregate<<<AGG_GRID, 1024, 0, stream>>>(
            state, (const __half2*)hs, off, packed, qctr, out);
    } else {
        float* agg = out + 3 * NSZ;
        (void)hipMemsetAsync(agg, 0, NSZ * sizeof(float), stream);
        edge_kernel<<<(N_EDGES * 4 + 255) / 256, 256, 0, stream>>>(
            state, row, col, w, agg);
        node_kernel<<<(N_NODES * 4 + 255) / 256, 256, 0, stream>>>(
            state, agg, out);
    }
}

// Round 13
// 173.256 us; speedup vs baseline: 1.6520x; 1.0530x over previous
//
#include <hip/hip_runtime.h>
#include <hip/hip_fp16.h>
#include <math.h>

#define N_NODES 100000
#define N_EDGES 3200000
#define DIM 16
#define NSZ (N_NODES * DIM)

#define NPB 128         // nodes per bucket (bucket = col>>7, cl = col&127)
#define NBUCK 782       // ceil(100000/128); last bucket has 32 valid nodes
#define NBLK 512        // sort partition blocks
#define EPB 6256        // edges per partition block; multiple of 4 for int4
#define MAXCAP 5120     // fixed per-bucket region (mean 4096 + 16 sigma)
#define CAP 4864        // aggregate LDS tile (buckets are ~always single-tile)
#define PRK 5           // ceil(CAP/1024) register-carried entries per thread

// packed entry: [63:47]=col(17) [46:30]=row(17) [29:0]=w bits>>2
typedef float nvec4 __attribute__((ext_vector_type(4)));

// ---- 1) prep: pure streaming — f32 state -> f16 table (3.2MB, reused by
//         aggregate); out1=x, out2=-x. No edge work (R12 lesson: histogram
//         lives in sort_write now, col read once total). ----
__global__ __launch_bounds__(512)
void prep(const float* __restrict__ state, __half* __restrict__ hs,
          float* __restrict__ out) {
    int i = blockIdx.x * 512 + threadIdx.x;
    if (i >= NSZ / 4) return;
    nvec4 v = __builtin_nontemporal_load(&((const nvec4*)state)[i]);
    union { __half2 h[2]; float2 f; } u;
    u.h[0] = __floats2half2_rn(v.x, v.y);
    u.h[1] = __floats2half2_rn(v.z, v.w);
    ((float2*)hs)[i] = u.f;                     // keep cached
    __builtin_nontemporal_store(v, &((nvec4*)(out + 1 * (size_t)NSZ))[i]);
    nvec4 nv = {-v.x, -v.y, -v.z, -v.w};
    __builtin_nontemporal_store(nv, &((nvec4*)(out + 2 * (size_t)NSZ))[i]);
}

// ---- 2) sort_write: self-contained. Per-block LDS histogram -> local scan
//         -> ONE global atomicAdd per non-empty bucket reserves a slot range
//         in the fixed [bucket*MAXCAP] region (cnt[] doubles as final bucket
//         totals for aggregate) -> LDS radix scatter -> dense sweep writes
//         runs of ~8 entries (full 64B lines). ----
__global__ __launch_bounds__(512)
void sort_write(const int* __restrict__ row, const int* __restrict__ col,
                const float* __restrict__ w, int* __restrict__ cnt,
                unsigned long long* __restrict__ packed) {
    __shared__ unsigned long long sbuf[EPB];   // 50,048 B
    __shared__ int cur[NBUCK];                 // hist -> scatter cursor
    __shared__ int diff[NBUCK];                // j*MAXCAP + base - lstart
    __shared__ int wsum[8];                    // ~56.4 KB total
    int t = threadIdx.x, blk = blockIdx.x;
    int e0 = blk * EPB;
    int eN = e0 + EPB; if (eN > N_EDGES) eN = N_EDGES;
    int ecnt = eN - e0;
    int nch = ecnt >> 2;
    const int4*   c4p = (const int4*)(col + e0);
    const int4*   r4p = (const int4*)(row + e0);
    const float4* w4p = (const float4*)(w + e0);

    for (int j = t; j < NBUCK; j += 512) cur[j] = 0;
    __syncthreads();
    for (int i = t; i < nch; i += 512) {       // local histogram
        int4 c = c4p[i];
        atomicAdd(&cur[c.x >> 7], 1);
        atomicAdd(&cur[c.y >> 7], 1);
        atomicAdd(&cur[c.z >> 7], 1);
        atomicAdd(&cur[c.w >> 7], 1);
    }
    __syncthreads();
    {   // pairwise shfl exclusive scan + global slot reservation
        int i0 = 2 * t, i1 = 2 * t + 1;
        int v0 = (i0 < NBUCK) ? cur[i0] : 0;
        int v1 = (i1 < NBUCK) ? cur[i1] : 0;
        int p = v0 + v1, ps = p;
        #pragma unroll
        for (int d = 1; d < 64; d <<= 1) {
            int u = __shfl_up(ps, d, 64);
            if ((t & 63) >= d) ps += u;
        }
        if ((t & 63) == 63) wsum[t >> 6] = ps;
        __syncthreads();
        int wid = t >> 6, wbase = 0;
        #pragma unroll
        for (int k = 0; k < 8; ++k) wbase += (k < wid) ? wsum[k] : 0;
        int ex = wbase + ps - p;               // lstart for i0
        if (i0 < NBUCK) {
            if (v0) {
                int base = atomicAdd(&cnt[i0], v0);
                diff[i0] = i0 * MAXCAP + base - ex;
            }
            cur[i0] = ex;
        }
        if (i1 < NBUCK) {
            if (v1) {
                int base = atomicAdd(&cnt[i1], v1);
                diff[i1] = i1 * MAXCAP + base - (ex + v0);
            }
            cur[i1] = ex + v0;
        }
    }
    __syncthreads();
    for (int i = t; i < nch; i += 512) {       // LDS radix scatter
        int4 c = c4p[i]; int4 r = r4p[i]; float4 ww = w4p[i];
        int pos;
        pos = atomicAdd(&cur[c.x >> 7], 1);
        sbuf[pos] = ((unsigned long long)(unsigned)c.x << 47)
                  | ((unsigned long long)(unsigned)r.x << 30)
                  | (unsigned long long)(__float_as_uint(ww.x) >> 2);
        pos = atomicAdd(&cur[c.y >> 7], 1);
        sbuf[pos] = ((unsigned long long)(unsigned)c.y << 47)
                  | ((unsigned long long)(unsigned)r.y << 30)
                  | (unsigned long long)(__float_as_uint(ww.y) >> 2);
        pos = atomicAdd(&cur[c.z >> 7], 1);
        sbuf[pos] = ((unsigned long long)(unsigned)c.z << 47)
                  | ((unsigned long long)(unsigned)r.z << 30)
                  | (unsigned long long)(__float_as_uint(ww.z) >> 2);
        pos = atomicAdd(&cur[c.w >> 7], 1);
        sbuf[pos] = ((unsigned long long)(unsigned)c.w << 47)
                  | ((unsigned long long)(unsigned)r.w << 30)
                  | (unsigned long long)(__float_as_uint(ww.w) >> 2);
    }
    __syncthreads();
    for (int i = t; i < ecnt; i += 512) {      // dense sweep; bucket from entry
        unsigned long long pv = sbuf[i];
        int b = (int)(pv >> 54);               // col>>7
        __builtin_nontemporal_store(pv, &packed[diff[b] + i]);
    }
}

// ---- 3) aggregate: 782 blocks x 1024 thr (R10-proven non-persistent form).
//         128 nodes x 4 dim-lanes x 2 edge-subgroups; f16 gather table
//         L2-resident; sin hidden under gather latency. ----
__global__ __launch_bounds__(1024, 8)
void aggregate(const float* __restrict__ state, const __half2* __restrict__ hs2,
               const int* __restrict__ cnt,
               const unsigned long long* __restrict__ packed,
               float* __restrict__ out) {
    __shared__ unsigned long long sbuf[CAP];       // 38,912 B
    __shared__ int s_cnt[NPB], s_start[NPB], s_cur[NPB];
    __shared__ int s_wsum;
    int nb = blockIdx.x, t = threadIdx.x;
    int q = t & 3, sub = (t >> 2) & 1, g = t >> 3;   // node group 0..127
    int beg = nb * MAXCAP;
    int end = beg + cnt[nb];
    int n = nb * NPB + g;
    bool valid = (n < N_NODES);
    float4 xx = valid ? ((const float4*)state)[n * 4 + q]
                      : make_float4(0.f, 0.f, 0.f, 0.f);
    float4 acc = {0.f, 0.f, 0.f, 0.f};
    const uint2* hsu = (const uint2*)hs2;            // 8 B = 4 halfs per lane

    for (int tbeg = beg; tbeg < end; tbeg += CAP) {
        int tend = tbeg + CAP; if (tend > end) tend = end;
        if (t < NPB) s_cnt[t] = 0;
        __syncthreads();

        // phase 1: coalesced read into registers; LDS cl-histogram
        unsigned long long pr[PRK];
        #pragma unroll
        for (int k = 0; k < PRK; ++k) {
            int e = tbeg + t + k * 1024;
            if (e < tend) {
                pr[k] = __builtin_nontemporal_load(&packed[e]);
                atomicAdd(&s_cnt[(unsigned)(pr[k] >> 47) & 127u], 1);
            }
        }
        __syncthreads();

        // phase 2: 128-entry exclusive scan on waves 0,1
        {
            int v = 0, ps = 0;
            if (t < NPB) {
                v = s_cnt[t]; ps = v;
                #pragma unroll
                for (int d = 1; d < 64; d <<= 1) {
                    int u = __shfl_up(ps, d, 64);
                    if ((t & 63) >= d) ps += u;
                }
            }
            if (t == 63) s_wsum = ps;
            __syncthreads();
            if (t < NPB) {
                int ex = ps - v + ((t >= 64) ? s_wsum : 0);
                s_start[t] = ex;
                s_cur[t] = ex;
            }
        }
        __syncthreads();

        // phase 3: scatter from registers
        #pragma unroll
        for (int k = 0; k < PRK; ++k) {
            int e = tbeg + t + k * 1024;
            if (e < tend) {
                int cl = (int)((pr[k] >> 47) & 127u);
                int pos = atomicAdd(&s_cur[cl], 1);
                sbuf[pos] = pr[k];
            }
        }
        __syncthreads();

        // phase 4: owner-computes; subgroup takes every 2nd edge, unroll-4
        {
            int es = s_start[g], ee = s_cur[g];
            int e = es + sub;
            for (; e + 6 < ee; e += 8) {
                unsigned long long p0 = sbuf[e];
                unsigned long long p1 = sbuf[e + 2];
                unsigned long long p2 = sbuf[e + 4];
                unsigned long long p3 = sbuf[e + 6];
                uint2 h0 = hsu[(unsigned)((p0 >> 30) & 0x1FFFFu) * 4u + q];
                uint2 h1 = hsu[(unsigned)((p1 >> 30) & 0x1FFFFu) * 4u + q];
                uint2 h2 = hsu[(unsigned)((p2 >> 30) & 0x1FFFFu) * 4u + q];
                uint2 h3 = hsu[(unsigned)((p3 >> 30) & 0x1FFFFu) * 4u + q];
                #pragma unroll
                for (int j = 0; j < 4; ++j) {
                    unsigned long long p = (j == 0) ? p0 : (j == 1) ? p1
                                         : (j == 2) ? p2 : p3;
                    uint2 hb = (j == 0) ? h0 : (j == 1) ? h1
                             : (j == 2) ? h2 : h3;
                    float we = __uint_as_float(((unsigned)p & 0x3FFFFFFFu) << 2);
                    float2 lo = __half22float2(*(const __half2*)&hb.x);
                    float2 hi = __half22float2(*(const __half2*)&hb.y);
                    acc.x += __sinf(lo.x - xx.x) * we;
                    acc.y += __sinf(lo.y - xx.y) * we;
                    acc.z += __sinf(hi.x - xx.z) * we;
                    acc.w += __sinf(hi.y - xx.w) * we;
                }
            }
            for (; e < ee; e += 2) {
                unsigned long long p = sbuf[e];
                uint2 hb = hsu[(unsigned)((p >> 30) & 0x1FFFFu) * 4u + q];
                float we = __uint_as_float(((unsigned)p & 0x3FFFFFFFu) << 2);
                float2 lo = __half22float2(*(const __half2*)&hb.x);
                float2 hi = __half22float2(*(const __half2*)&hb.y);
                acc.x += __sinf(lo.x - xx.x) * we;
                acc.y += __sinf(lo.y - xx.y) * we;
                acc.z += __sinf(hi.x - xx.z) * we;
                acc.w += __sinf(hi.y - xx.w) * we;
            }
        }
        __syncthreads();
    }

    // merge 2 subgroups (lanes t, t^4 — same wave, same g and q)
    acc.x += __shfl_xor(acc.x, 4, 64); acc.y += __shfl_xor(acc.y, 4, 64);
    acc.z += __shfl_xor(acc.z, 4, 64); acc.w += __shfl_xor(acc.w, 4, 64);

    if (valid && sub == 0) {
        // sub0 lanes write consecutive 16B chunks: full 64B lines per wave
        float4 th = make_float4(tanhf(acc.x), tanhf(acc.y),
                                tanhf(acc.z), tanhf(acc.w));
        int gdx = n * 4 + q;
        nvec4 v0 = {th.x - xx.x, th.y - xx.y, th.z - xx.z, th.w - xx.w};
        nvec4 v3 = {acc.x, acc.y, acc.z, acc.w};
        nvec4 v4 = {th.x, th.y, th.z, th.w};
        __builtin_nontemporal_store(v0, &((nvec4*)(out + 0 * (size_t)NSZ))[gdx]);
        __builtin_nontemporal_store(v3, &((nvec4*)(out + 3 * (size_t)NSZ))[gdx]);
        __builtin_nontemporal_store(v4, &((nvec4*)(out + 4 * (size_t)NSZ))[gdx]);
    }
}

// ---- fallback (tiny ws): atomic path ----
__global__ __launch_bounds__(256)
void edge_kernel(const float* __restrict__ state, const int* __restrict__ row,
                 const int* __restrict__ col, const float* __restrict__ w,
                 float* __restrict__ agg) {
    int idx = blockIdx.x * blockDim.x + threadIdx.x;
    if (idx >= N_EDGES * 4) return;
    int e = idx >> 2, qq = idx & 3;
    int r = row[e], c = col[e];
    float we = w[e];
    const float4 xr = ((const float4*)state)[r * 4 + qq];
    const float4 xcv = ((const float4*)state)[c * 4 + qq];
    float* dst = agg + c * DIM + qq * 4;
    atomicAdd(dst + 0, sinf(xr.x - xcv.x) * we);
    atomicAdd(dst + 1, sinf(xr.y - xcv.y) * we);
    atomicAdd(dst + 2, sinf(xr.z - xcv.z) * we);
    atomicAdd(dst + 3, sinf(xr.w - xcv.w) * we);
}

__global__ __launch_bounds__(256)
void node_kernel(const float* __restrict__ state, const float* __restrict__ agg,
                 float* __restrict__ out) {
    int idx = blockIdx.x * blockDim.x + threadIdx.x;
    if (idx >= N_NODES * 4) return;
    float4 x = ((const float4*)state)[idx];
    float4 a = ((const float4*)agg)[idx];
    float4 tv = make_float4(tanhf(a.x), tanhf(a.y), tanhf(a.z), tanhf(a.w));
    ((float4*)(out + 0 * NSZ))[idx] = make_float4(tv.x - x.x, tv.y - x.y,
                                                  tv.z - x.z, tv.w - x.w);
    ((float4*)(out + 1 * NSZ))[idx] = x;
    ((float4*)(out + 2 * NSZ))[idx] = make_float4(-x.x, -x.y, -x.z, -x.w);
    ((float4*)(out + 4 * NSZ))[idx] = tv;
}

extern "C" void kernel_launch(void* const* d_in, const int* in_sizes, int n_in,
                              void* d_out, int out_size, void* d_ws, size_t ws_size,
                              hipStream_t stream) {
    const float* state = (const float*)d_in[0];
    const int*   row   = (const int*)d_in[1];
    const int*   col   = (const int*)d_in[2];
    const float* w     = (const float*)d_in[3];
    float* out = (float*)d_out;

    // ws: packed [NBUCK][MAXCAP] | hs (f16 state) | cnt
    size_t packed_off = 0;
    size_t hs_off     = packed_off + (size_t)NBUCK * MAXCAP * 8;   // 32.0MB
    size_t cnt_off    = hs_off + (size_t)NSZ * 2;                  // +3.2MB
    size_t needed     = cnt_off + (size_t)NBUCK * 4;

    if (ws_size >= needed) {
        unsigned long long* packed =
            (unsigned long long*)((char*)d_ws + packed_off);
        __half* hs = (__half*)((char*)d_ws + hs_off);
        int* cnt   = (int*)((char*)d_ws + cnt_off);

        (void)hipMemsetAsync(cnt, 0, (size_t)NBUCK * sizeof(int), stream);
        prep<<<(NSZ / 4 + 511) / 512, 512, 0, stream>>>(state, hs, out);
        sort_write<<<NBLK, 512, 0, stream>>>(row, col, w, cnt, packed);
        aggregate<<<NBUCK, 1024, 0, stream>>>(
            state, (const __half2*)hs, cnt, packed, out);
    } else {
        float* agg = out + 3 * NSZ;
        (void)hipMemsetAsync(agg, 0, NSZ * sizeof(float), stream);
        edge_kernel<<<(N_EDGES * 4 + 255) / 256, 256, 0, stream>>>(
            state, row, col, w, agg);
        node_kernel<<<(N_NODES * 4 + 255) / 256, 256, 0, stream>>>(
            state, agg, out);
    }
}

// Round 14
// 162.041 us; speedup vs baseline: 1.7664x; 1.0692x over previous
//
#include <hip/hip_runtime.h>
#include <hip/hip_fp16.h>
#include <math.h>

#define N_NODES 100000
#define N_EDGES 3200000
#define DIM 16
#define NSZ (N_NODES * DIM)

#define NPB 128         // nodes per bucket (bucket = col>>7, cl = col&127)
#define NBUCK 782       // ceil(100000/128); last bucket has 32 valid nodes
#define NBLK 512        // sort partition blocks
#define EPB 6256        // edges per partition block; multiple of 4 for int4
#define MAXCAP 5120     // fixed per-bucket region (mean 4096 + 16 sigma)
#define CAP 4864        // aggregate LDS tile (buckets are ~always single-tile)
#define PRK 5           // ceil(CAP/1024) register-carried entries per thread

// packed entry: [63:47]=col(17) [46:30]=row(17) [29:0]=w bits>>2
typedef float nvec4 __attribute__((ext_vector_type(4)));

// ---- 1) prep: pure streaming — f32 state -> f16 table (3.2MB, reused by
//         aggregate); out1=x, out2=-x. ----
__global__ __launch_bounds__(512)
void prep(const float* __restrict__ state, __half* __restrict__ hs,
          float* __restrict__ out) {
    int i = blockIdx.x * 512 + threadIdx.x;
    if (i >= NSZ / 4) return;
    nvec4 v = __builtin_nontemporal_load(&((const nvec4*)state)[i]);
    union { __half2 h[2]; float2 f; } u;
    u.h[0] = __floats2half2_rn(v.x, v.y);
    u.h[1] = __floats2half2_rn(v.z, v.w);
    ((float2*)hs)[i] = u.f;                     // keep cached
    __builtin_nontemporal_store(v, &((nvec4*)(out + 1 * (size_t)NSZ))[i]);
    nvec4 nv = {-v.x, -v.y, -v.z, -v.w};
    __builtin_nontemporal_store(nv, &((nvec4*)(out + 2 * (size_t)NSZ))[i]);
}

#define PACK(c, r, ww) (((unsigned long long)(unsigned)(c) << 47)             \
                      | ((unsigned long long)(unsigned)(r) << 30)             \
                      | (unsigned long long)(__float_as_uint(ww) >> 2))

// ---- 2) sort_write: register-carried edges, LDS histogram (3.1KB only) ->
//         one global atomicAdd per non-empty bucket reserves a PRIVATE
//         contiguous sub-range in [bucket*MAXCAP] -> direct scatter from
//         registers with PLAIN stores (block-private lines: L2 combines).
//         No sbuf, no scan, no sweep (R13 lesson: 56KB LDS = 2 blocks/CU
//         = pure stall at VALUBusy 4%). cnt[] doubles as bucket totals. ----
__global__ __launch_bounds__(512)
void sort_write(const int* __restrict__ row, const int* __restrict__ col,
                const float* __restrict__ w, int* __restrict__ cnt,
                unsigned long long* __restrict__ packed) {
    __shared__ int cur[NBUCK];                 // hist -> absolute cursor
    int t = threadIdx.x, blk = blockIdx.x;
    int e0 = blk * EPB;
    int eN = e0 + EPB; if (eN > N_EDGES) eN = N_EDGES;
    int nch = (eN - e0) >> 2;                  // (eN-e0) % 4 == 0 always
    const int4*   c4p = (const int4*)(col + e0);
    const int4*   r4p = (const int4*)(row + e0);
    const float4* w4p = (const float4*)(w + e0);

    for (int j = t; j < NBUCK; j += 512) cur[j] = 0;
    __syncthreads();

    // phase 1: load + pack into registers (static indices) + LDS histogram
    unsigned long long pr[16];
    #pragma unroll
    for (int k = 0; k < 4; ++k) {
        int i = t + k * 512;
        if (i < nch) {
            int4 c = c4p[i]; int4 r = r4p[i]; float4 ww = w4p[i];
            pr[4 * k + 0] = PACK(c.x, r.x, ww.x);
            pr[4 * k + 1] = PACK(c.y, r.y, ww.y);
            pr[4 * k + 2] = PACK(c.z, r.z, ww.z);
            pr[4 * k + 3] = PACK(c.w, r.w, ww.w);
            atomicAdd(&cur[c.x >> 7], 1);
            atomicAdd(&cur[c.y >> 7], 1);
            atomicAdd(&cur[c.z >> 7], 1);
            atomicAdd(&cur[c.w >> 7], 1);
        }
    }
    __syncthreads();

    // phase 2: one global reservation per non-empty bucket; cur becomes
    // the absolute write cursor for this block's private sub-range
    for (int j = t; j < NBUCK; j += 512) {
        int v = cur[j];
        if (v) cur[j] = j * MAXCAP + atomicAdd(&cnt[j], v);
    }
    __syncthreads();

    // phase 3: direct scatter from registers (plain stores -> L2 combines)
    #pragma unroll
    for (int k = 0; k < 4; ++k) {
        int i = t + k * 512;
        if (i < nch) {
            #pragma unroll
            for (int j = 0; j < 4; ++j) {
                unsigned long long pv = pr[4 * k + j];
                int b = (int)(pv >> 54);       // col>>7
                int pos = atomicAdd(&cur[b], 1);
                packed[pos] = pv;
            }
        }
    }
}

// ---- 3) aggregate: 782 blocks x 1024 thr (R10-proven form).
//         128 nodes x 4 dim-lanes x 2 edge-subgroups; f16 gather table
//         L2-resident; sin hidden under gather latency. ----
__global__ __launch_bounds__(1024, 8)
void aggregate(const float* __restrict__ state, const __half2* __restrict__ hs2,
               const int* __restrict__ cnt,
               const unsigned long long* __restrict__ packed,
               float* __restrict__ out) {
    __shared__ unsigned long long sbuf[CAP];       // 38,912 B
    __shared__ int s_cnt[NPB], s_start[NPB], s_cur[NPB];
    __shared__ int s_wsum;
    int nb = blockIdx.x, t = threadIdx.x;
    int q = t & 3, sub = (t >> 2) & 1, g = t >> 3;   // node group 0..127
    int beg = nb * MAXCAP;
    int end = beg + cnt[nb];
    int n = nb * NPB + g;
    bool valid = (n < N_NODES);
    float4 xx = valid ? ((const float4*)state)[n * 4 + q]
                      : make_float4(0.f, 0.f, 0.f, 0.f);
    float4 acc = {0.f, 0.f, 0.f, 0.f};
    const uint2* hsu = (const uint2*)hs2;            // 8 B = 4 halfs per lane

    for (int tbeg = beg; tbeg < end; tbeg += CAP) {
        int tend = tbeg + CAP; if (tend > end) tend = end;
        if (t < NPB) s_cnt[t] = 0;
        __syncthreads();

        // phase 1: coalesced read into registers; LDS cl-histogram
        unsigned long long pr[PRK];
        #pragma unroll
        for (int k = 0; k < PRK; ++k) {
            int e = tbeg + t + k * 1024;
            if (e < tend) {
                pr[k] = __builtin_nontemporal_load(&packed[e]);
                atomicAdd(&s_cnt[(unsigned)(pr[k] >> 47) & 127u], 1);
            }
        }
        __syncthreads();

        // phase 2: 128-entry exclusive scan on waves 0,1
        {
            int v = 0, ps = 0;
            if (t < NPB) {
                v = s_cnt[t]; ps = v;
                #pragma unroll
                for (int d = 1; d < 64; d <<= 1) {
                    int u = __shfl_up(ps, d, 64);
                    if ((t & 63) >= d) ps += u;
                }
            }
            if (t == 63) s_wsum = ps;
            __syncthreads();
            if (t < NPB) {
                int ex = ps - v + ((t >= 64) ? s_wsum : 0);
                s_start[t] = ex;
                s_cur[t] = ex;
            }
        }
        __syncthreads();

        // phase 3: scatter from registers
        #pragma unroll
        for (int k = 0; k < PRK; ++k) {
            int e = tbeg + t + k * 1024;
            if (e < tend) {
                int cl = (int)((pr[k] >> 47) & 127u);
                int pos = atomicAdd(&s_cur[cl], 1);
                sbuf[pos] = pr[k];
            }
        }
        __syncthreads();

        // phase 4: owner-computes; subgroup takes every 2nd edge, unroll-4
        {
            int es = s_start[g], ee = s_cur[g];
            int e = es + sub;
            for (; e + 6 < ee; e += 8) {
                unsigned long long p0 = sbuf[e];
                unsigned long long p1 = sbuf[e + 2];
                unsigned long long p2 = sbuf[e + 4];
                unsigned long long p3 = sbuf[e + 6];
                uint2 h0 = hsu[(unsigned)((p0 >> 30) & 0x1FFFFu) * 4u + q];
                uint2 h1 = hsu[(unsigned)((p1 >> 30) & 0x1FFFFu) * 4u + q];
                uint2 h2 = hsu[(unsigned)((p2 >> 30) & 0x1FFFFu) * 4u + q];
                uint2 h3 = hsu[(unsigned)((p3 >> 30) & 0x1FFFFu) * 4u + q];
                #pragma unroll
                for (int j = 0; j < 4; ++j) {
                    unsigned long long p = (j == 0) ? p0 : (j == 1) ? p1
                                         : (j == 2) ? p2 : p3;
                    uint2 hb = (j == 0) ? h0 : (j == 1) ? h1
                             : (j == 2) ? h2 : h3;
                    float we = __uint_as_float(((unsigned)p & 0x3FFFFFFFu) << 2);
                    float2 lo = __half22float2(*(const __half2*)&hb.x);
                    float2 hi = __half22float2(*(const __half2*)&hb.y);
                    acc.x += __sinf(lo.x - xx.x) * we;
                    acc.y += __sinf(lo.y - xx.y) * we;
                    acc.z += __sinf(hi.x - xx.z) * we;
                    acc.w += __sinf(hi.y - xx.w) * we;
                }
            }
            for (; e < ee; e += 2) {
                unsigned long long p = sbuf[e];
                uint2 hb = hsu[(unsigned)((p >> 30) & 0x1FFFFu) * 4u + q];
                float we = __uint_as_float(((unsigned)p & 0x3FFFFFFFu) << 2);
                float2 lo = __half22float2(*(const __half2*)&hb.x);
                float2 hi = __half22float2(*(const __half2*)&hb.y);
                acc.x += __sinf(lo.x - xx.x) * we;
                acc.y += __sinf(lo.y - xx.y) * we;
                acc.z += __sinf(hi.x - xx.z) * we;
                acc.w += __sinf(hi.y - xx.w) * we;
            }
        }
        __syncthreads();
    }

    // merge 2 subgroups (lanes t, t^4 — same wave, same g and q)
    acc.x += __shfl_xor(acc.x, 4, 64); acc.y += __shfl_xor(acc.y, 4, 64);
    acc.z += __shfl_xor(acc.z, 4, 64); acc.w += __shfl_xor(acc.w, 4, 64);

    if (valid && sub == 0) {
        // sub0 lanes write consecutive 16B chunks: full 64B lines per wave
        float4 th = make_float4(tanhf(acc.x), tanhf(acc.y),
                                tanhf(acc.z), tanhf(acc.w));
        int gdx = n * 4 + q;
        nvec4 v0 = {th.x - xx.x, th.y - xx.y, th.z - xx.z, th.w - xx.w};
        nvec4 v3 = {acc.x, acc.y, acc.z, acc.w};
        nvec4 v4 = {th.x, th.y, th.z, th.w};
        __builtin_nontemporal_store(v0, &((nvec4*)(out + 0 * (size_t)NSZ))[gdx]);
        __builtin_nontemporal_store(v3, &((nvec4*)(out + 3 * (size_t)NSZ))[gdx]);
        __builtin_nontemporal_store(v4, &((nvec4*)(out + 4 * (size_t)NSZ))[gdx]);
    }
}

// ---- fallback (tiny ws): atomic path ----
__global__ __launch_bounds__(256)
void edge_kernel(const float* __restrict__ state, const int* __restrict__ row,
                 const int* __restrict__ col, const float* __restrict__ w,
                 float* __restrict__ agg) {
    int idx = blockIdx.x * blockDim.x + threadIdx.x;
    if (idx >= N_EDGES * 4) return;
    int e = idx >> 2, qq = idx & 3;
    int r = row[e], c = col[e];
    float we = w[e];
    const float4 xr = ((const float4*)state)[r * 4 + qq];
    const float4 xcv = ((const float4*)state)[c * 4 + qq];
    float* dst = agg + c * DIM + qq * 4;
    atomicAdd(dst + 0, sinf(xr.x - xcv.x) * we);
    atomicAdd(dst + 1, sinf(xr.y - xcv.y) * we);
    atomicAdd(dst + 2, sinf(xr.z - xcv.z) * we);
    atomicAdd(dst + 3, sinf(xr.w - xcv.w) * we);
}

__global__ __launch_bounds__(256)
void node_kernel(const float* __restrict__ state, const float* __restrict__ agg,
                 float* __restrict__ out) {
    int idx = blockIdx.x * blockDim.x + threadIdx.x;
    if (idx >= N_NODES * 4) return;
    float4 x = ((const float4*)state)[idx];
    float4 a = ((const float4*)agg)[idx];
    float4 tv = make_float4(tanhf(a.x), tanhf(a.y), tanhf(a.z), tanhf(a.w));
    ((float4*)(out + 0 * NSZ))[idx] = make_float4(tv.x - x.x, tv.y - x.y,
                                                  tv.z - x.z, tv.w - x.w);
    ((float4*)(out + 1 * NSZ))[idx] = x;
    ((float4*)(out + 2 * NSZ))[idx] = make_float4(-x.x, -x.y, -x.z, -x.w);
    ((float4*)(out + 4 * NSZ))[idx] = tv;
}

extern "C" void kernel_launch(void* const* d_in, const int* in_sizes, int n_in,
                              void* d_out, int out_size, void* d_ws, size_t ws_size,
                              hipStream_t stream) {
    const float* state = (const float*)d_in[0];
    const int*   row   = (const int*)d_in[1];
    const int*   col   = (const int*)d_in[2];
    const float* w     = (const float*)d_in[3];
    float* out = (float*)d_out;

    // ws: packed [NBUCK][MAXCAP] | hs (f16 state) | cnt
    size_t packed_off = 0;
    size_t hs_off     = packed_off + (size_t)NBUCK * MAXCAP * 8;   // 32.0MB
    size_t cnt_off    = hs_off + (size_t)NSZ * 2;                  // +3.2MB
    size_t needed     = cnt_off + (size_t)NBUCK * 4;

    if (ws_size >= needed) {
        unsigned long long* packed =
            (unsigned long long*)((char*)d_ws + packed_off);
        __half* hs = (__half*)((char*)d_ws + hs_off);
        int* cnt   = (int*)((char*)d_ws + cnt_off);

        (void)hipMemsetAsync(cnt, 0, (size_t)NBUCK * sizeof(int), stream);
        prep<<<(NSZ / 4 + 511) / 512, 512, 0, stream>>>(state, hs, out);
        sort_write<<<NBLK, 512, 0, stream>>>(row, col, w, cnt, packed);
        aggregate<<<NBUCK, 1024, 0, stream>>>(
            state, (const __half2*)hs, cnt, packed, out);
    } else {
        float* agg = out + 3 * NSZ;
        (void)hipMemsetAsync(agg, 0, NSZ * sizeof(float), stream);
        edge_kernel<<<(N_EDGES * 4 + 255) / 256, 256, 0, stream>>>(
            state, row, col, w, agg);
        node_kernel<<<(N_NODES * 4 + 255) / 256, 256, 0, stream>>>(
            state, agg, out);
    }
}